// Round 1
// 1245.445 us; speedup vs baseline: 1.1807x; 1.1807x over previous
//
#include <hip/hip_runtime.h>
#include <stdint.h>

typedef __bf16   bf16x8 __attribute__((ext_vector_type(8)));
typedef float    f32x4  __attribute__((ext_vector_type(4)));
typedef uint32_t u32x4  __attribute__((ext_vector_type(4)));

#define L_SEQ 8192
#define DIM   768
#define DROW  8768     // dupG row length in dwords (zero-padded tail)
// dupG[d][i] = ( k[8223-i], k[8222-i] ) as packed bf16 pair, scaled by 1/16384.
// k[s]=0 for s<0 or s>8191  ->  dupG zero for i<31 and i>=8224.

// Workspace layout (bytes):
//   dupG u32  [768][8768]    @ 0            size 26,935,296
//   uT   bf16 [768][8][8192] @ 26,935,296   size 100,663,296
//   yT   bf16 [768][8][8192] @ 127,598,592  size 100,663,296
// total 228,261,888 B

// ---------------- zero the dupG pad regions (re-poisoned every call) ------
__global__ __launch_bounds__(256) void pad_kernel(uint32_t* __restrict__ dupG)
{
  int d = blockIdx.x;
  const int NPAD = 31 + (DROW - 8224);
  for (int j = threadIdx.x; j < NPAD; j += 256) {
    int i = (j < 31) ? j : 8224 + (j - 31);
    dupG[(size_t)d * DROW + i] = 0u;
  }
}

// ---------------- filter MLP -> dupG pairs --------------------------------
// block c covers s in [32c, 32c+31]; computes K[j] = k[32c-1+j], j in [0,33)
__global__ __launch_bounds__(256) void filter_kernel(
    const float* __restrict__ w_in, const float* __restrict__ b_in,
    const float* __restrict__ freq_in,
    const float* __restrict__ w_h0, const float* __restrict__ b_h0,
    const float* __restrict__ freq_h0,
    const float* __restrict__ w_h1, const float* __restrict__ b_h1,
    const float* __restrict__ freq_h1,
    const float* __restrict__ w_out,
    uint32_t* __restrict__ dupG)
{
  __shared__ float h1[33][65];
  __shared__ float h2[33][65];
  __shared__ unsigned short kv[33][64];
  __shared__ float wch[64][64];           // w_out chunk [r][dd]

  const int c = blockIdx.x;               // 0..255
  const int sbase = c << 5;
  const int tid = threadIdx.x;

  // layer 1 (EMB=3 features)
  for (int p = tid; p < 33 * 64; p += 256) {
    int j = p >> 6, n = p & 63;
    int s = sbase - 1 + j;
    float t  = s * (1.0f / 8191.0f);
    float ph = s * (float)(6.283185307179586 * 1e-4 / 8192.0);
    float a = t * w_in[n] + cosf(ph) * w_in[64 + n] + (-sinf(ph)) * w_in[128 + n] + b_in[n];
    h1[j][n] = sinf(freq_in[n] * a);
  }
  __syncthreads();
  for (int p = tid; p < 33 * 64; p += 256) {
    int j = p >> 6, n = p & 63;
    float a = b_h0[n];
    for (int r = 0; r < 64; ++r) a += h1[j][r] * w_h0[r * 64 + n];
    h2[j][n] = sinf(freq_h0[n] * a);
  }
  __syncthreads();
  for (int p = tid; p < 33 * 64; p += 256) {
    int j = p >> 6, n = p & 63;
    float a = b_h1[n];
    for (int r = 0; r < 64; ++r) a += h2[j][r] * w_h1[r * 64 + n];
    h1[j][n] = sinf(freq_h1[n] * a);      // h1 <- h3
  }
  __syncthreads();

  for (int dc = 0; dc < 12; ++dc) {
    for (int p = tid; p < 64 * 64; p += 256) {
      int r = p >> 6, dd = p & 63;
      wch[r][dd] = w_out[r * DIM + dc * 64 + dd];
    }
    __syncthreads();
    for (int p = tid; p < 33 * 64; p += 256) {
      int j = p >> 6, dd = p & 63;
      float a = 0.0f;
      for (int r = 0; r < 64; ++r) a += h1[j][r] * wch[r][dd];
      int s = sbase - 1 + j;
      int d = dc * 64 + dd;
      float delta = fabsf(-3.070113457f - 12.280453827f * (d * (1.0f / 767.0f)));
      float t = s * (1.0f / 8191.0f);
      float val = (s < 0) ? 0.0f : a * expf(-t * delta) * 6.103515625e-05f;
      kv[j][dd] = __builtin_bit_cast(unsigned short, (__bf16)val);
    }
    __syncthreads();
    // dup[8223-s] = (k[s], k[s-1]) for s = sbase+j, j in [0,32)
    for (int p = tid; p < 32 * 64; p += 256) {
      int j = p >> 6, dd = p & 63;
      int d = dc * 64 + dd;
      int i = 8223 - (sbase + j);
      dupG[(size_t)d * DROW + i] =
          (uint32_t)kv[j + 1][dd] | ((uint32_t)kv[j][dd] << 16);
    }
    if (c == 255 && tid < 64) {
      int d = dc * 64 + tid;
      dupG[(size_t)d * DROW + 31] = ((uint32_t)kv[32][tid] << 16); // (0, k[8191])
    }
    __syncthreads();
  }
}

// ---------------- x (B,L,D) fp32 -> uT[d][b][t] bf16 ----------------------
__global__ __launch_bounds__(256) void transpose_in_kernel(
    const float* __restrict__ x, unsigned short* __restrict__ uT)
{
  __shared__ unsigned short tile[64][66];
  int b = blockIdx.z;
  int t0 = blockIdx.y * 64;
  int d0 = blockIdx.x * 64;
  int tid = threadIdx.x;
  int j = tid & 63, i0 = tid >> 6;
  for (int ii = 0; ii < 16; ++ii) {
    int tt = i0 * 16 + ii;
    float v = x[((size_t)b * L_SEQ + t0 + tt) * DIM + d0 + j];
    tile[tt][j] = __builtin_bit_cast(unsigned short, (__bf16)v);
  }
  __syncthreads();
  for (int ii = 0; ii < 16; ++ii) {
    int dd = i0 + ii * 4;
    uT[((size_t)(d0 + dd) * 8 + b) * L_SEQ + t0 + j] = tile[j][dd];
  }
}

// ---------------- conv: yT[d][b][t] = sum_tau u[b][tau] k[t-tau] ----------
// t-span 512/block; 8 MFMA sub-tiles per wave; rolling B-fragments.
// Software-pipelined staging: the next 4-BODY group's 128-dword dG chunk is
// loaded into registers at group top (overlaps 32 MFMAs/wave of compute),
// written to LDS at group end, ONE barrier per group.
#define LOADFRAG(dst, absdw) {                                   \
    int _p = ((absdw) & 1023);                                   \
    u32x4 _u = { buf[_p], buf[_p + 2], buf[_p + 4], buf[_p + 6] };\
    dst = __builtin_bit_cast(bf16x8, _u); }

__global__ __launch_bounds__(256) void conv_kernel(
    const uint32_t* __restrict__ dupG,
    const unsigned short* __restrict__ uT,
    unsigned short* __restrict__ yT)
{
  const int d   = blockIdx.y;
  const int T0  = blockIdx.x << 9;       // t-span 512
  const int tid = threadIdx.x;
  const int lane = tid & 63;
  const int w    = tid >> 6;
  const int m = lane & 15, q = lane >> 4;
  __shared__ uint32_t buf[1056];         // 1024 circular + 32 mirror

  f32x4 acc[8] = {};
  bf16x8 fr[8];

  float delta = fabsf(-3.070113457f - 12.280453827f * (d * (1.0f / 767.0f)));
  int S = (int)(8191.0f * 3.5065578f / delta);   // decay < 0.03 cutoff
  int tau_start = T0 - S;
  tau_start = (tau_start < 0) ? 0 : (tau_start & ~31);
  int niter = ((T0 + 480 - tau_start) >> 5) + 1;
  niter = (niter + 3) & ~3;              // pad with zero-contribution iters

  const uint32_t* dG = dupG + (size_t)d * DROW;
  const unsigned short* uTd = uT + ((size_t)d << 16);

  int i0 = 7712 - T0 + tau_start;        // window base (dword idx), >= 32

  // prefill window [i0, i0+648): covers ALL reads of group 0
  // (max group-0 read = i0+637; i0 <= 7712 so i0+647 < 8768, pad region = 0)
  for (int j = tid; j < 648; j += 256) {
    int i = i0 + j;
    uint32_t v = dG[i];
    int pos = i & 1023;
    buf[pos] = v;
    if (pos < 32) buf[1024 + pos] = v;
  }
  __syncthreads();

  // per-lane bases
  int a_off = ((lane & 7) << 14) + ((tau_start + (q << 3)) << 1);  // bytes into uTd
  int vb = i0 + 511 - (w << 7) - m + (q << 3);                     // abs dword, st=0
  int chunk_i = i0 + 648;                // next chunk to stage (group g+1's data)

  // prologue: fragments for st=2..7 of iteration 0
  LOADFRAG(fr[6], vb - 32);
  LOADFRAG(fr[7], vb - 48);
  LOADFRAG(fr[4], vb - 64);
  LOADFRAG(fr[5], vb - 80);
  LOADFRAG(fr[2], vb - 96);
  LOADFRAG(fr[3], vb - 112);

#define MFMA_ST(rr, st)                                                        \
  acc[st] = __builtin_amdgcn_mfma_f32_16x16x32_bf16(                           \
      afrag, fr[(2 * (rr) - 2 * ((st) >> 1) + ((st) & 1)) & 7], acc[st], 0, 0, 0);

#define BODY(rr) {                                                             \
    bf16x8 afrag = *(const bf16x8*)((const char*)uTd + a_off + ((rr) << 6));   \
    int vbr = vb + ((rr) << 5);                                                \
    LOADFRAG(fr[(2 * (rr)) & 7], vbr);                                         \
    LOADFRAG(fr[(2 * (rr) + 1) & 7], vbr - 16);                                \
    MFMA_ST(rr, 2) MFMA_ST(rr, 3) MFMA_ST(rr, 4) MFMA_ST(rr, 5)                \
    MFMA_ST(rr, 6) MFMA_ST(rr, 7) MFMA_ST(rr, 0) MFMA_ST(rr, 1)               \
  }

  for (int nn = 0; nn < niter; nn += 4) {
    // stage next group's chunk [chunk_i, chunk_i+128) into registers;
    // latency overlaps the 4 BODYs below.
    uint32_t stage = 0u;
    int si = chunk_i + tid;
    if (tid < 128) {
      int iv = (si < 8744) ? si : 8744;  // clamp into zero tail
      stage = dG[iv];
    }
    // 4 BODYs: LDS reads + MFMAs only; window for all of them is resident.
    BODY(0) BODY(1) BODY(2) BODY(3)
    // commit staged chunk. Write region [i0+648+g*128,+128) mod 1024 is
    // disjoint from this group's read window [i0+g*128, i0+638+g*128) mod
    // 1024, and only aliases reads from 3 groups back -> one barrier/group.
    if (tid < 128) {
      int pos = si & 1023;
      buf[pos] = stage;
      if (pos < 32) buf[1024 + pos] = stage;
    }
    __syncthreads();
    a_off   += 256;   // 128 elements
    vb      += 128;   // dwords
    chunk_i += 128;
  }

  // C[row][col]: col = lane&15 = t-offset, row = (lane>>4)*4 + reg = batch
  if (q < 2) {
#pragma unroll
    for (int st = 0; st < 8; ++st) {
      int t0 = T0 + ((w * 8 + st) << 4);
#pragma unroll
      for (int r = 0; r < 4; ++r) {
        int bb = q * 4 + r;
        yT[((size_t)(d * 8 + bb) << 13) + t0 + m] =
            __builtin_bit_cast(unsigned short, (__bf16)acc[st][r]);
      }
    }
  }
}

// ---------------- yT[d][b][t] bf16 -> out (B,L,D) fp32 + bias -------------
__global__ __launch_bounds__(256) void transpose_out_kernel(
    const unsigned short* __restrict__ yT, const float* __restrict__ bias,
    float* __restrict__ out)
{
  __shared__ float tile[64][65];
  int b = blockIdx.z;
  int t0 = blockIdx.y * 64;
  int d0 = blockIdx.x * 64;
  int tid = threadIdx.x;
  int j = tid & 63, i0 = tid >> 6;
  for (int ii = 0; ii < 16; ++ii) {
    int dd = i0 * 16 + ii;
    unsigned short v = yT[((size_t)(d0 + dd) * 8 + b) * L_SEQ + t0 + j];
    tile[dd][j] = (float)__builtin_bit_cast(__bf16, v);
  }
  __syncthreads();
  float bs = bias[d0 + j];
  for (int ii = 0; ii < 16; ++ii) {
    int tt = i0 + ii * 4;
    out[((size_t)b * L_SEQ + t0 + tt) * DIM + d0 + j] = tile[j][tt] + bs;
  }
}

extern "C" void kernel_launch(void* const* d_in, const int* in_sizes, int n_in,
                              void* d_out, int out_size, void* d_ws, size_t ws_size,
                              hipStream_t stream)
{
  const float* x       = (const float*)d_in[0];
  const float* w_in    = (const float*)d_in[1];
  const float* b_in    = (const float*)d_in[2];
  const float* freq_in = (const float*)d_in[3];
  const float* w_h0    = (const float*)d_in[4];
  const float* b_h0    = (const float*)d_in[5];
  const float* freq_h0 = (const float*)d_in[6];
  const float* w_h1    = (const float*)d_in[7];
  const float* b_h1    = (const float*)d_in[8];
  const float* freq_h1 = (const float*)d_in[9];
  const float* w_out   = (const float*)d_in[10];
  const float* bias    = (const float*)d_in[11];

  char* ws = (char*)d_ws;
  uint32_t* dupG = (uint32_t*)(ws);
  unsigned short* uT = (unsigned short*)(ws + 26935296);
  unsigned short* yT = (unsigned short*)(ws + 127598592);
  float* out = (float*)d_out;

  hipLaunchKernelGGL(pad_kernel, dim3(DIM), dim3(256), 0, stream, dupG);
  hipLaunchKernelGGL(filter_kernel, dim3(256), dim3(256), 0, stream,
                     w_in, b_in, freq_in, w_h0, b_h0, freq_h0,
                     w_h1, b_h1, freq_h1, w_out, dupG);
  hipLaunchKernelGGL(transpose_in_kernel, dim3(12, 128, 8), dim3(256), 0, stream, x, uT);
  hipLaunchKernelGGL(conv_kernel, dim3(16, DIM), dim3(256), 0, stream, dupG, uT, yT);
  hipLaunchKernelGGL(transpose_out_kernel, dim3(12, 128, 8), dim3(256), 0, stream,
                     yT, bias, out);
}

// Round 2
// 933.061 us; speedup vs baseline: 1.5760x; 1.3348x over previous
//
#include <hip/hip_runtime.h>
#include <stdint.h>

typedef __bf16   bf16x8 __attribute__((ext_vector_type(8)));
typedef float    f32x4  __attribute__((ext_vector_type(4)));
typedef uint32_t u32x4  __attribute__((ext_vector_type(4)));

#define L_SEQ 8192
#define DIM   768
#define DROW  8768     // dupG row length in dwords (zero-padded tail)
// dupG[d][i] = ( k[8223-i] in lo16, k[8222-i] in hi16 ), scaled by 1/16384.
// k[s]=0 for s<0 or s>8191  ->  dupG zero for i<31 and i>=8224.

// Workspace layout (bytes):
//   dupG u32  [768][8768]    @ 0            size 26,935,296
//   uT   bf16 [768][8][8192] @ 26,935,296   size 100,663,296
//   yT   bf16 [768][8][8192] @ 127,598,592  size 100,663,296
// total 228,261,888 B

// ---------------- zero the dupG pad regions (re-poisoned every call) ------
__global__ __launch_bounds__(256) void pad_kernel(uint32_t* __restrict__ dupG)
{
  int d = blockIdx.x;
  const int NPAD = 31 + (DROW - 8224);
  for (int j = threadIdx.x; j < NPAD; j += 256) {
    int i = (j < 31) ? j : 8224 + (j - 31);
    dupG[(size_t)d * DROW + i] = 0u;
  }
}

// ---------------- filter MLP -> dupG pairs --------------------------------
__global__ __launch_bounds__(256) void filter_kernel(
    const float* __restrict__ w_in, const float* __restrict__ b_in,
    const float* __restrict__ freq_in,
    const float* __restrict__ w_h0, const float* __restrict__ b_h0,
    const float* __restrict__ freq_h0,
    const float* __restrict__ w_h1, const float* __restrict__ b_h1,
    const float* __restrict__ freq_h1,
    const float* __restrict__ w_out,
    uint32_t* __restrict__ dupG)
{
  __shared__ float h1[33][65];
  __shared__ float h2[33][65];
  __shared__ unsigned short kv[33][64];
  __shared__ float wch[64][64];

  const int c = blockIdx.x;               // 0..255
  const int sbase = c << 5;
  const int tid = threadIdx.x;

  for (int p = tid; p < 33 * 64; p += 256) {
    int j = p >> 6, n = p & 63;
    int s = sbase - 1 + j;
    float t  = s * (1.0f / 8191.0f);
    float ph = s * (float)(6.283185307179586 * 1e-4 / 8192.0);
    float a = t * w_in[n] + cosf(ph) * w_in[64 + n] + (-sinf(ph)) * w_in[128 + n] + b_in[n];
    h1[j][n] = sinf(freq_in[n] * a);
  }
  __syncthreads();
  for (int p = tid; p < 33 * 64; p += 256) {
    int j = p >> 6, n = p & 63;
    float a = b_h0[n];
    for (int r = 0; r < 64; ++r) a += h1[j][r] * w_h0[r * 64 + n];
    h2[j][n] = sinf(freq_h0[n] * a);
  }
  __syncthreads();
  for (int p = tid; p < 33 * 64; p += 256) {
    int j = p >> 6, n = p & 63;
    float a = b_h1[n];
    for (int r = 0; r < 64; ++r) a += h2[j][r] * w_h1[r * 64 + n];
    h1[j][n] = sinf(freq_h1[n] * a);
  }
  __syncthreads();

  for (int dc = 0; dc < 12; ++dc) {
    for (int p = tid; p < 64 * 64; p += 256) {
      int r = p >> 6, dd = p & 63;
      wch[r][dd] = w_out[r * DIM + dc * 64 + dd];
    }
    __syncthreads();
    for (int p = tid; p < 33 * 64; p += 256) {
      int j = p >> 6, dd = p & 63;
      float a = 0.0f;
      for (int r = 0; r < 64; ++r) a += h1[j][r] * wch[r][dd];
      int s = sbase - 1 + j;
      int d = dc * 64 + dd;
      float delta = fabsf(-3.070113457f - 12.280453827f * (d * (1.0f / 767.0f)));
      float t = s * (1.0f / 8191.0f);
      float val = (s < 0) ? 0.0f : a * expf(-t * delta) * 6.103515625e-05f;
      kv[j][dd] = __builtin_bit_cast(unsigned short, (__bf16)val);
    }
    __syncthreads();
    for (int p = tid; p < 32 * 64; p += 256) {
      int j = p >> 6, dd = p & 63;
      int d = dc * 64 + dd;
      int i = 8223 - (sbase + j);
      dupG[(size_t)d * DROW + i] =
          (uint32_t)kv[j + 1][dd] | ((uint32_t)kv[j][dd] << 16);
    }
    if (c == 255 && tid < 64) {
      int d = dc * 64 + tid;
      dupG[(size_t)d * DROW + 31] = ((uint32_t)kv[32][tid] << 16);
    }
    __syncthreads();
  }
}

// ---------------- x (B,L,D) fp32 -> uT[d][b][t] bf16 ----------------------
__global__ __launch_bounds__(256) void transpose_in_kernel(
    const float* __restrict__ x, unsigned short* __restrict__ uT)
{
  __shared__ unsigned short tile[64][66];
  int b = blockIdx.z;
  int t0 = blockIdx.y * 64;
  int d0 = blockIdx.x * 64;
  int tid = threadIdx.x;
  int j = tid & 63, i0 = tid >> 6;
  for (int ii = 0; ii < 16; ++ii) {
    int tt = i0 * 16 + ii;
    float v = x[((size_t)b * L_SEQ + t0 + tt) * DIM + d0 + j];
    tile[tt][j] = __builtin_bit_cast(unsigned short, (__bf16)v);
  }
  __syncthreads();
  for (int ii = 0; ii < 16; ++ii) {
    int dd = i0 + ii * 4;
    uT[((size_t)(d0 + dd) * 8 + b) * L_SEQ + t0 + j] = tile[j][dd];
  }
}

// ---------------- conv: yT[d][b][t] = sum_tau u[b][tau] k[t-tau] ----------
// t-span 1024/block; packed-M: MFMA rows = (batch b, half h), h=1 rows
// compute t+16 with u-window shifted +16 (same B fragment, Toeplitz).
// 8 merged tiles/wave, 8-body groups, one barrier per group.
#define LOADFRAG(dst, absdw) {                                    \
    int _p = ((absdw) & 2047);                                    \
    u32x4 _u = { buf[_p], buf[_p + 2], buf[_p + 4], buf[_p + 6] };\
    dst = __builtin_bit_cast(bf16x8, _u); }

__global__ __launch_bounds__(256) void conv_kernel(
    const uint32_t* __restrict__ dupG,
    const unsigned short* __restrict__ uT,
    unsigned short* __restrict__ yT)
{
  const int d   = blockIdx.y;
  const int T0  = blockIdx.x << 10;      // t-span 1024
  const int tid = threadIdx.x;
  const int lane = tid & 63;
  const int w    = tid >> 6;
  const int m = lane & 15, q = lane >> 4;
  const int h = (lane >> 3) & 1;         // = (m >> 3)
  __shared__ uint32_t buf[2080];         // 2048 circular + 32 mirror

  f32x4 acc[8] = {};
  bf16x8 fr2[8];
  bf16x8 zfr = {};

  float delta = fabsf(-3.070113457f - 12.280453827f * (d * (1.0f / 767.0f)));
  int S = (int)(8191.0f * 3.5065578f / delta);   // decay < 0.03 cutoff
  int tau_start = T0 - S;
  tau_start = (tau_start < 0) ? 0 : (tau_start & ~31);
  int niter = ((T0 + 992 - tau_start) >> 5) + 1; // = (T0+1024-tau_start)/32
  niter = (niter + 7) & ~7;              // pad with zero-contribution iters

  const uint32_t* dG = dupG + (size_t)d * DROW;
  const unsigned short* uTd = uT + ((size_t)d << 16);

  int i0 = 7200 + tau_start - T0;        // window base (dword idx), >= 32

  // prefill window [i0, i0+1280): covers all reads of group 0 (max i0+1255)
  for (int j = tid; j < 1280; j += 256) {
    int i = i0 + j;
    uint32_t v = dG[i];
    int pos = i & 2047;
    buf[pos] = v;
    if (pos < 32) buf[2048 + pos] = v;
  }
  __syncthreads();

  // A element base: tau = tau_start - 16 + 16h + 8q (h=0 rows shifted -16;
  // kill-mask handles tau<0 when tau_start==0). Row stride 16 KiB (8192 bf16).
  int a_off = ((lane & 7) << 14) + ((tau_start - 16 + (h << 4) + (q << 3)) << 1);
  int vb = i0 + 1007 - (w << 8) - m + (q << 3);   // abs dword, body 0, tile 0
  int chunk_i = i0 + 1280;

  const bool kill = (tau_start == 0) & (h == 0) & (q < 2);  // tau<0 taps, body 0 only

  // prologue: fragments for tiles j=1..7 of body 0
  LOADFRAG(fr2[7], vb - 32);
  LOADFRAG(fr2[6], vb - 64);
  LOADFRAG(fr2[5], vb - 96);
  LOADFRAG(fr2[4], vb - 128);
  LOADFRAG(fr2[3], vb - 160);
  LOADFRAG(fr2[2], vb - 192);
  LOADFRAG(fr2[1], vb - 224);

#define MFMA_J(rr, j)                                                          \
  acc[j] = __builtin_amdgcn_mfma_f32_16x16x32_bf16(                            \
      afrag, fr2[((rr) - (j)) & 7], acc[j], 0, 0, 0);

#define BODY(rr, K0) {                                                         \
    bf16x8 afrag = *(const bf16x8*)((const char*)uTd + a_off + ((rr) << 6));   \
    if (K0) { if (kill) afrag = zfr; }                                         \
    LOADFRAG(fr2[(rr) & 7], vb + ((rr) << 5));                                 \
    MFMA_J(rr, 1) MFMA_J(rr, 2) MFMA_J(rr, 3) MFMA_J(rr, 4)                    \
    MFMA_J(rr, 5) MFMA_J(rr, 6) MFMA_J(rr, 7) MFMA_J(rr, 0)                    \
  }

  // group 0: body 0 carries the tau<0 kill-mask
  {
    int si = chunk_i + tid;
    int iv = (si < 8744) ? si : 8744;    // clamp into zero tail
    uint32_t stage = dG[iv];
    BODY(0, 1) BODY(1, 0) BODY(2, 0) BODY(3, 0)
    BODY(4, 0) BODY(5, 0) BODY(6, 0) BODY(7, 0)
    int pos = si & 2047;
    buf[pos] = stage;
    if (pos < 32) buf[2048 + pos] = stage;
    __syncthreads();
    a_off += 512; vb += 256; chunk_i += 256;
  }
  for (int nn = 8; nn < niter; nn += 8) {
    int si = chunk_i + tid;
    int iv = (si < 8744) ? si : 8744;
    uint32_t stage = dG[iv];
    BODY(0, 0) BODY(1, 0) BODY(2, 0) BODY(3, 0)
    BODY(4, 0) BODY(5, 0) BODY(6, 0) BODY(7, 0)
    int pos = si & 2047;
    buf[pos] = stage;
    if (pos < 32) buf[2048 + pos] = stage;
    __syncthreads();
    a_off += 512; vb += 256; chunk_i += 256;
  }

  // C[row][col]: col = m = t-offset(16), row = q*4+r = (b, h):
  //   y[b][T0 + 256w + 32j + 16h + m]
#pragma unroll
  for (int j = 0; j < 8; ++j) {
    int tb_ = T0 + (w << 8) + (j << 5) + m;
#pragma unroll
    for (int r = 0; r < 4; ++r) {
      int row = q * 4 + r;
      int bb = row & 7;
      int hh = row >> 3;
      yT[((size_t)(d * 8 + bb) << 13) + tb_ + (hh << 4)] =
          __builtin_bit_cast(unsigned short, (__bf16)acc[j][r]);
    }
  }
}

// ---------------- yT[d][b][t] bf16 -> out (B,L,D) fp32 + bias -------------
__global__ __launch_bounds__(256) void transpose_out_kernel(
    const unsigned short* __restrict__ yT, const float* __restrict__ bias,
    float* __restrict__ out)
{
  __shared__ float tile[64][65];
  int b = blockIdx.z;
  int t0 = blockIdx.y * 64;
  int d0 = blockIdx.x * 64;
  int tid = threadIdx.x;
  int j = tid & 63, i0 = tid >> 6;
  for (int ii = 0; ii < 16; ++ii) {
    int dd = i0 * 16 + ii;
    unsigned short v = yT[((size_t)(d0 + dd) * 8 + b) * L_SEQ + t0 + j];
    tile[dd][j] = (float)__builtin_bit_cast(__bf16, v);
  }
  __syncthreads();
  float bs = bias[d0 + j];
  for (int ii = 0; ii < 16; ++ii) {
    int tt = i0 + ii * 4;
    out[((size_t)b * L_SEQ + t0 + tt) * DIM + d0 + j] = tile[j][tt] + bs;
  }
}

extern "C" void kernel_launch(void* const* d_in, const int* in_sizes, int n_in,
                              void* d_out, int out_size, void* d_ws, size_t ws_size,
                              hipStream_t stream)
{
  const float* x       = (const float*)d_in[0];
  const float* w_in    = (const float*)d_in[1];
  const float* b_in    = (const float*)d_in[2];
  const float* freq_in = (const float*)d_in[3];
  const float* w_h0    = (const float*)d_in[4];
  const float* b_h0    = (const float*)d_in[5];
  const float* freq_h0 = (const float*)d_in[6];
  const float* w_h1    = (const float*)d_in[7];
  const float* b_h1    = (const float*)d_in[8];
  const float* freq_h1 = (const float*)d_in[9];
  const float* w_out   = (const float*)d_in[10];
  const float* bias    = (const float*)d_in[11];

  char* ws = (char*)d_ws;
  uint32_t* dupG = (uint32_t*)(ws);
  unsigned short* uT = (unsigned short*)(ws + 26935296);
  unsigned short* yT = (unsigned short*)(ws + 127598592);
  float* out = (float*)d_out;

  hipLaunchKernelGGL(pad_kernel, dim3(DIM), dim3(256), 0, stream, dupG);
  hipLaunchKernelGGL(filter_kernel, dim3(256), dim3(256), 0, stream,
                     w_in, b_in, freq_in, w_h0, b_h0, freq_h0,
                     w_h1, b_h1, freq_h1, w_out, dupG);
  hipLaunchKernelGGL(transpose_in_kernel, dim3(12, 128, 8), dim3(256), 0, stream, x, uT);
  hipLaunchKernelGGL(conv_kernel, dim3(8, DIM), dim3(256), 0, stream, dupG, uT, yT);
  hipLaunchKernelGGL(transpose_out_kernel, dim3(12, 128, 8), dim3(256), 0, stream,
                     yT, bias, out);
}